// Round 5
// baseline (108.119 us; speedup 1.0000x reference)
//
#include <hip/hip_runtime.h>

namespace {
constexpr int Bsz = 32;
constexpr int Ssz = 128;
constexpr int Hsz = 768;
constexpr int Msz = 8;     // max span width
constexpr int MHs = 6;     // holder max width
constexpr int NSPAN = Msz * Ssz; // 1024
}

__device__ __forceinline__ bool gtpair(float av, int ai, float bv, int bi) {
    // strict "ranks higher": greater value, or equal value with lower index (stable)
    return (av > bv) || (av == bv && ai < bi);
}

struct Top4 { float v[4]; int ix[4]; };

__device__ __forceinline__ void t4_init(Top4& t) {
#pragma unroll
    for (int k = 0; k < 4; ++k) { t.v[k] = -3.f; t.ix[k] = 0x7fffffff; }
}

// Static-index insert: candidate (cv,ci) into sorted-descending list.
// Pure compare+select — no dynamic array subscripts (avoids scratch).
__device__ __forceinline__ void t4_insert_g(Top4& a, float cv, int ci) {
    bool g0 = gtpair(cv, ci, a.v[0], a.ix[0]);
    bool g1 = gtpair(cv, ci, a.v[1], a.ix[1]);
    bool g2 = gtpair(cv, ci, a.v[2], a.ix[2]);
    bool g3 = gtpair(cv, ci, a.v[3], a.ix[3]);
    float nv3 = g2 ? a.v[2]  : (g3 ? cv : a.v[3]);
    int   ni3 = g2 ? a.ix[2] : (g3 ? ci : a.ix[3]);
    float nv2 = g1 ? a.v[1]  : (g2 ? cv : a.v[2]);
    int   ni2 = g1 ? a.ix[1] : (g2 ? ci : a.ix[2]);
    float nv1 = g0 ? a.v[0]  : (g1 ? cv : a.v[1]);
    int   ni1 = g0 ? a.ix[0] : (g1 ? ci : a.ix[1]);
    float nv0 = g0 ? cv : a.v[0];
    int   ni0 = g0 ? ci : a.ix[0];
    a.v[0] = nv0; a.ix[0] = ni0;
    a.v[1] = nv1; a.ix[1] = ni1;
    a.v[2] = nv2; a.ix[2] = ni2;
    a.v[3] = nv3; a.ix[3] = ni3;
}

// Merge sorted-descending b into a by rank-order insertion (static indices only).
__device__ __forceinline__ void t4_merge_into(Top4& a, const Top4& b) {
#pragma unroll
    for (int k = 0; k < 4; ++k) t4_insert_g(a, b.v[k], b.ix[k]);
}

__device__ __forceinline__ Top4 t4_wave_merge(Top4 t) {
#pragma unroll
    for (int off = 1; off < 64; off <<= 1) {
        Top4 o;
#pragma unroll
        for (int k = 0; k < 4; ++k) {
            o.v[k]  = __shfl_xor(t.v[k], off);
            o.ix[k] = __shfl_xor(t.ix[k], off);
        }
        t4_merge_into(t, o);
    }
    return t;
}

// Fused: one block per batch. Phase A computes per-row dots (row_dots fused),
// then scores + static-network top-4 + batched-load projections + logits.
__global__ __launch_bounds__(256) void per_batch_fused(
    const float* __restrict__ emb, const int* __restrict__ mask,
    const float* __restrict__ wh, const float* __restrict__ bh_p,
    const float* __restrict__ wt, const float* __restrict__ bt_p,
    const float* __restrict__ wi, const float* __restrict__ bi,
    const float* __restrict__ we, const float* __restrict__ be,
    float* __restrict__ out)
{
    const int b = blockIdx.x;
    const int tid = threadIdx.x;
    const int wavei = tid >> 6, lane = tid & 63;

    __shared__ float dsh[Ssz], dst_[Ssz];
    __shared__ int   len_s;
    __shared__ float swv[4][4];
    __shared__ int   swi[4][4];
    __shared__ int   sel[8];       // 0..3 targets, 4..7 holders
    __shared__ int   val[8];
    __shared__ float proj[8][8];

    // ---- phase A: per-row dual dots, wave w handles rows 32w..32w+31 ----
    int mcnt = 0;
    if (wavei == 0)
        mcnt = mask[b * Ssz + lane] + mask[b * Ssz + lane + 64];

    const float4* wh4 = (const float4*)wh;
    const float4* wt4 = (const float4*)wt;
    float4 WH0 = wh4[lane], WH1 = wh4[lane + 64], WH2 = wh4[lane + 128];
    float4 WT0 = wt4[lane], WT1 = wt4[lane + 64], WT2 = wt4[lane + 128];

    const float4* eb = (const float4*)(emb + (size_t)b * Ssz * Hsz);
#pragma unroll 4
    for (int r8 = 0; r8 < 32; ++r8) {
        int row = wavei * 32 + r8;
        const float4* rp = eb + row * (Hsz / 4);
        float4 e0 = rp[lane], e1 = rp[lane + 64], e2 = rp[lane + 128];
        float ph = 0.f, pt = 0.f;
        ph = fmaf(e0.x, WH0.x, fmaf(e0.y, WH0.y, fmaf(e0.z, WH0.z, fmaf(e0.w, WH0.w, ph))));
        ph = fmaf(e1.x, WH1.x, fmaf(e1.y, WH1.y, fmaf(e1.z, WH1.z, fmaf(e1.w, WH1.w, ph))));
        ph = fmaf(e2.x, WH2.x, fmaf(e2.y, WH2.y, fmaf(e2.z, WH2.z, fmaf(e2.w, WH2.w, ph))));
        pt = fmaf(e0.x, WT0.x, fmaf(e0.y, WT0.y, fmaf(e0.z, WT0.z, fmaf(e0.w, WT0.w, pt))));
        pt = fmaf(e1.x, WT1.x, fmaf(e1.y, WT1.y, fmaf(e1.z, WT1.z, fmaf(e1.w, WT1.w, pt))));
        pt = fmaf(e2.x, WT2.x, fmaf(e2.y, WT2.y, fmaf(e2.z, WT2.z, fmaf(e2.w, WT2.w, pt))));
#pragma unroll
        for (int off = 32; off; off >>= 1) {
            ph += __shfl_down(ph, off);
            pt += __shfl_down(pt, off);
        }
        if (lane == 0) { dsh[row] = ph; dst_[row] = pt; }
    }
    if (wavei == 0) {
#pragma unroll
        for (int off = 32; off; off >>= 1) mcnt += __shfl_down(mcnt, off);
        if (lane == 0) len_s = mcnt;
    }
    __syncthreads();                                        // barrier 1

    const int   len = len_s;
    const float bhv = bh_p[0], btv = bt_p[0];
    float* out_impl = out;                                  // [B,4,4]
    float* out_expl = out + Bsz * 16;                       // [B,16,4]
    float* out_hs   = out_expl + Bsz * 64;                  // [B,1024]
    float* out_ts   = out_hs + Bsz * NSPAN;                 // [B,1024]

    // ---- phase 1: thread = (start, grp); grp 0 (waves 0-1) = targets,
    // grp 1 (waves 2-3) = holders. Running sum over widths 1..8; candidates
    // generated in ascending span index (stable: insert_g keeps lower index on tie).
    {
        const int st  = tid & (Ssz - 1);
        const int grp = tid >> 7;
        const float* dar = grp ? dsh : dst_;
        const float  bv  = grp ? bhv : btv;
        float* outp = grp ? (out_hs + b * NSPAN) : (out_ts + b * NSPAN);
        Top4 t4l; t4_init(t4l);
        float run = 0.f;
#pragma unroll
        for (int widx = 0; widx < Msz; ++widx) {
            bool fits = (st < len - widx);
            if (fits) run += dar[st + widx];       // st+widx < len <= Ssz, in-bounds
            bool valid = fits && (grp == 0 || widx < MHs);
            float sc = -1.f;
            if (valid) {
                float x = run * (1.f / (float)(widx + 1)) + bv;
                sc = 1.f / (1.f + __expf(-x));
            }
            int i = (widx << 7) | st;
            outp[i] = sc;
            t4_insert_g(t4l, sc, i);
        }
        t4l = t4_wave_merge(t4l);
        if (lane == 0) {
#pragma unroll
            for (int k = 0; k < 4; ++k) { swv[wavei][k] = t4l.v[k]; swi[wavei][k] = t4l.ix[k]; }
        }
    }
    __syncthreads();                                        // barrier 2

    // cross-wave merge: tid 0 -> targets (waves 0,1 -> slots 0..3),
    //                   tid 1 -> holders (waves 2,3 -> slots 4..7)
    if (tid < 2) {
        Top4 a, c;
#pragma unroll
        for (int k = 0; k < 4; ++k) {
            a.v[k] = swv[2 * tid][k];     a.ix[k] = swi[2 * tid][k];
            c.v[k] = swv[2 * tid + 1][k]; c.ix[k] = swi[2 * tid + 1][k];
        }
        t4_merge_into(a, c);
#pragma unroll
        for (int k = 0; k < 4; ++k) {
            sel[tid * 4 + k] = a.ix[k];
            val[tid * 4 + k] = (a.v[k] > 0.f) ? 1 : 0;
        }
    }
    __syncthreads();                                        // barrier 3

    // ---- phase 2: projections — wave handles slot wavei (target) then wavei+4
    // (holder). Span rows are L1/L2-hot from phase A. All loads unrolled+clamped.
    for (int s2 = 0; s2 < 2; ++s2) {
        int slot = wavei + 4 * s2;
        float acc[8] = {0.f, 0.f, 0.f, 0.f, 0.f, 0.f, 0.f, 0.f};
        if (val[slot]) {                                    // wave-uniform branch
            int idx = sel[slot];
            int w = (idx >> 7) + 1, st = idx & (Ssz - 1);
            const float4* base = eb + (size_t)st * (Hsz / 4);
            float inv = 1.f / (float)w;
            float4 s0 = {0,0,0,0}, s1 = {0,0,0,0}, s2v = {0,0,0,0};
#pragma unroll
            for (int r = 0; r < Msz; ++r) {
                int   rr = (r < w) ? r : (w - 1);           // clamped: always a valid row
                float m_ = (r < w) ? inv : 0.f;
                const float4* rp = base + rr * (Hsz / 4);
                float4 e0 = rp[lane];
                float4 e1 = rp[lane + 64];
                float4 e2 = rp[lane + 128];
                s0.x = fmaf(e0.x, m_, s0.x); s0.y = fmaf(e0.y, m_, s0.y);
                s0.z = fmaf(e0.z, m_, s0.z); s0.w = fmaf(e0.w, m_, s0.w);
                s1.x = fmaf(e1.x, m_, s1.x); s1.y = fmaf(e1.y, m_, s1.y);
                s1.z = fmaf(e1.z, m_, s1.z); s1.w = fmaf(e1.w, m_, s1.w);
                s2v.x = fmaf(e2.x, m_, s2v.x); s2v.y = fmaf(e2.y, m_, s2v.y);
                s2v.z = fmaf(e2.z, m_, s2v.z); s2v.w = fmaf(e2.w, m_, s2v.w);
            }
            const float4* wi4 = (const float4*)wi;          // [Hsz][4] -> one float4 per row
            const float4* we4 = (const float4*)we;          // [2*Hsz][4]
#pragma unroll
            for (int ii = 0; ii < 3; ++ii) {
                float4 rep = (ii == 0) ? s0 : ((ii == 1) ? s1 : s2v);
                float reps[4] = {rep.x, rep.y, rep.z, rep.w};
                int j = lane + 64 * ii;                     // float4 index; elements 4j..4j+3
                if (s2 == 0) {                              // target: wi + we bottom half
#pragma unroll
                    for (int t = 0; t < 4; ++t) {
                        float rt = reps[t];
                        float4 a = wi4[4 * j + t];
                        float4 c = we4[Hsz + 4 * j + t];
                        acc[0] = fmaf(rt, a.x, acc[0]); acc[1] = fmaf(rt, a.y, acc[1]);
                        acc[2] = fmaf(rt, a.z, acc[2]); acc[3] = fmaf(rt, a.w, acc[3]);
                        acc[4] = fmaf(rt, c.x, acc[4]); acc[5] = fmaf(rt, c.y, acc[5]);
                        acc[6] = fmaf(rt, c.z, acc[6]); acc[7] = fmaf(rt, c.w, acc[7]);
                    }
                } else {                                    // holder: we top half
#pragma unroll
                    for (int t = 0; t < 4; ++t) {
                        float rt = reps[t];
                        float4 c = we4[4 * j + t];
                        acc[0] = fmaf(rt, c.x, acc[0]); acc[1] = fmaf(rt, c.y, acc[1]);
                        acc[2] = fmaf(rt, c.z, acc[2]); acc[3] = fmaf(rt, c.w, acc[3]);
                    }
                }
            }
        }
#pragma unroll
        for (int off = 32; off; off >>= 1)
#pragma unroll
            for (int c = 0; c < 8; ++c) acc[c] += __shfl_down(acc[c], off);
        if (lane == 0)
#pragma unroll
            for (int c = 0; c < 8; ++c) proj[slot][c] = acc[c];
    }
    __syncthreads();                                        // barrier 4

    // ---- phase 3: final logits ----
    if (tid < 16) {                 // implicit: [4 targets][4 cols]
        int k = tid >> 2, c = tid & 3;
        out_impl[b * 16 + tid] = bi[c] + (val[k] ? proj[k][c] : 0.f);
    } else if (tid >= 64 && tid < 128) {  // explicit: [4 holders][4 targets][4 cols]
        int u = tid - 64;
        int j = u >> 4, k = (u >> 2) & 3, c = u & 3;
        float v = be[c];
        if (val[4 + j] && val[k]) v += proj[4 + j][c] + proj[k][4 + c];
        out_expl[b * 64 + u] = v;
    }
}

extern "C" void kernel_launch(void* const* d_in, const int* in_sizes, int n_in,
                              void* d_out, int out_size, void* d_ws, size_t ws_size,
                              hipStream_t stream) {
    const float* emb  = (const float*)d_in[0];
    const int*   mask = (const int*)d_in[1];
    const float* wh   = (const float*)d_in[2];
    const float* bh   = (const float*)d_in[3];
    const float* wt   = (const float*)d_in[4];
    const float* bt   = (const float*)d_in[5];
    const float* wi   = (const float*)d_in[6];
    const float* bi   = (const float*)d_in[7];
    const float* we   = (const float*)d_in[8];
    const float* be   = (const float*)d_in[9];
    float* out = (float*)d_out;

    per_batch_fused<<<Bsz, 256, 0, stream>>>(emb, mask, wh, bh, wt, bt,
                                             wi, bi, we, be, out);
}

// Round 6
// 93.339 us; speedup vs baseline: 1.1584x; 1.1584x over previous
//
#include <hip/hip_runtime.h>

namespace {
constexpr int Bsz = 32;
constexpr int Ssz = 128;
constexpr int Hsz = 768;
constexpr int Msz = 8;     // max span width
constexpr int MHs = 6;     // holder max width
constexpr int NSPAN = Msz * Ssz; // 1024
}

__device__ __forceinline__ bool gtpair(float av, int ai, float bv, int bi) {
    // strict "ranks higher": greater value, or equal value with lower index (stable)
    return (av > bv) || (av == bv && ai < bi);
}

struct Top4 { float v[4]; int ix[4]; };

__device__ __forceinline__ void t4_init(Top4& t) {
#pragma unroll
    for (int k = 0; k < 4; ++k) { t.v[k] = -3.f; t.ix[k] = 0x7fffffff; }
}

// Static-index insert: candidate (cv,ci) into sorted-descending list.
// Pure compare+select — no dynamic array subscripts (avoids scratch).
__device__ __forceinline__ void t4_insert_g(Top4& a, float cv, int ci) {
    bool g0 = gtpair(cv, ci, a.v[0], a.ix[0]);
    bool g1 = gtpair(cv, ci, a.v[1], a.ix[1]);
    bool g2 = gtpair(cv, ci, a.v[2], a.ix[2]);
    bool g3 = gtpair(cv, ci, a.v[3], a.ix[3]);
    float nv3 = g2 ? a.v[2]  : (g3 ? cv : a.v[3]);
    int   ni3 = g2 ? a.ix[2] : (g3 ? ci : a.ix[3]);
    float nv2 = g1 ? a.v[1]  : (g2 ? cv : a.v[2]);
    int   ni2 = g1 ? a.ix[1] : (g2 ? ci : a.ix[2]);
    float nv1 = g0 ? a.v[0]  : (g1 ? cv : a.v[1]);
    int   ni1 = g0 ? a.ix[0] : (g1 ? ci : a.ix[1]);
    float nv0 = g0 ? cv : a.v[0];
    int   ni0 = g0 ? ci : a.ix[0];
    a.v[0] = nv0; a.ix[0] = ni0;
    a.v[1] = nv1; a.ix[1] = ni1;
    a.v[2] = nv2; a.ix[2] = ni2;
    a.v[3] = nv3; a.ix[3] = ni3;
}

// Merge sorted-descending b into a by rank-order insertion (static indices only).
__device__ __forceinline__ void t4_merge_into(Top4& a, const Top4& b) {
#pragma unroll
    for (int k = 0; k < 4; ++k) t4_insert_g(a, b.v[k], b.ix[k]);
}

__device__ __forceinline__ Top4 t4_wave_merge(Top4 t) {
#pragma unroll
    for (int off = 1; off < 64; off <<= 1) {
        Top4 o;
#pragma unroll
        for (int k = 0; k < 4; ++k) {
            o.v[k]  = __shfl_xor(t.v[k], off);
            o.ix[k] = __shfl_xor(t.ix[k], off);
        }
        t4_merge_into(t, o);
    }
    return t;
}

// K1: dh[row] = emb[row,:]·wh, dt[row] = emb[row,:]·wt
// 2 rows per wave (6 independent load streams), grid 512 x 4 waves = 1024 rows x2.
__global__ __launch_bounds__(256) void row_dots_kernel(
    const float* __restrict__ emb, const float* __restrict__ wh,
    const float* __restrict__ wt, float* __restrict__ dh, float* __restrict__ dt)
{
    int wave = blockIdx.x * 4 + (threadIdx.x >> 6);   // 0..2047
    int lane = threadIdx.x & 63;
    int row0 = wave * 2;

    const float4* wh4 = (const float4*)wh;
    const float4* wt4 = (const float4*)wt;
    float4 WH0 = wh4[lane], WH1 = wh4[lane + 64], WH2 = wh4[lane + 128];
    float4 WT0 = wt4[lane], WT1 = wt4[lane + 64], WT2 = wt4[lane + 128];

    const float4* r0 = (const float4*)(emb + (size_t)row0 * Hsz);
    const float4* r1 = r0 + (Hsz / 4);
    float4 a0 = r0[lane], a1 = r0[lane + 64], a2 = r0[lane + 128];
    float4 b0 = r1[lane], b1 = r1[lane + 64], b2 = r1[lane + 128];

    float ph0 = 0.f, pt0 = 0.f, ph1 = 0.f, pt1 = 0.f;
    ph0 = fmaf(a0.x, WH0.x, fmaf(a0.y, WH0.y, fmaf(a0.z, WH0.z, fmaf(a0.w, WH0.w, ph0))));
    ph0 = fmaf(a1.x, WH1.x, fmaf(a1.y, WH1.y, fmaf(a1.z, WH1.z, fmaf(a1.w, WH1.w, ph0))));
    ph0 = fmaf(a2.x, WH2.x, fmaf(a2.y, WH2.y, fmaf(a2.z, WH2.z, fmaf(a2.w, WH2.w, ph0))));
    pt0 = fmaf(a0.x, WT0.x, fmaf(a0.y, WT0.y, fmaf(a0.z, WT0.z, fmaf(a0.w, WT0.w, pt0))));
    pt0 = fmaf(a1.x, WT1.x, fmaf(a1.y, WT1.y, fmaf(a1.z, WT1.z, fmaf(a1.w, WT1.w, pt0))));
    pt0 = fmaf(a2.x, WT2.x, fmaf(a2.y, WT2.y, fmaf(a2.z, WT2.z, fmaf(a2.w, WT2.w, pt0))));
    ph1 = fmaf(b0.x, WH0.x, fmaf(b0.y, WH0.y, fmaf(b0.z, WH0.z, fmaf(b0.w, WH0.w, ph1))));
    ph1 = fmaf(b1.x, WH1.x, fmaf(b1.y, WH1.y, fmaf(b1.z, WH1.z, fmaf(b1.w, WH1.w, ph1))));
    ph1 = fmaf(b2.x, WH2.x, fmaf(b2.y, WH2.y, fmaf(b2.z, WH2.z, fmaf(b2.w, WH2.w, ph1))));
    pt1 = fmaf(b0.x, WT0.x, fmaf(b0.y, WT0.y, fmaf(b0.z, WT0.z, fmaf(b0.w, WT0.w, pt1))));
    pt1 = fmaf(b1.x, WT1.x, fmaf(b1.y, WT1.y, fmaf(b1.z, WT1.z, fmaf(b1.w, WT1.w, pt1))));
    pt1 = fmaf(b2.x, WT2.x, fmaf(b2.y, WT2.y, fmaf(b2.z, WT2.z, fmaf(b2.w, WT2.w, pt1))));

#pragma unroll
    for (int off = 32; off; off >>= 1) {
        ph0 += __shfl_down(ph0, off);
        pt0 += __shfl_down(pt0, off);
        ph1 += __shfl_down(ph1, off);
        pt1 += __shfl_down(pt1, off);
    }
    if (lane == 0) {
        dh[row0] = ph0; dt[row0] = pt0;
        dh[row0 + 1] = ph1; dt[row0 + 1] = pt1;
    }
}

// K2: one block per batch — scores, static-network top-4, batched-load projections.
__global__ __launch_bounds__(256) void per_batch_kernel(
    const float* __restrict__ emb, const int* __restrict__ mask,
    const float* __restrict__ bh_p, const float* __restrict__ bt_p,
    const float* __restrict__ wi, const float* __restrict__ bi,
    const float* __restrict__ we, const float* __restrict__ be,
    const float* __restrict__ dh, const float* __restrict__ dt,
    float* __restrict__ out)
{
    const int b = blockIdx.x;
    const int tid = threadIdx.x;
    const int wavei = tid >> 6, lane = tid & 63;

    __shared__ float dsh[Ssz], dst_[Ssz];
    __shared__ int   len_s;
    __shared__ float swv[4][4];
    __shared__ int   swi[4][4];
    __shared__ int   sel[8];       // 0..3 targets, 4..7 holders
    __shared__ int   val[8];
    __shared__ float proj[8][8];

    // phase 0: per-row dots into LDS; wave0 computes sentence length
    if (tid < Ssz) {
        dsh[tid]  = dh[b * Ssz + tid];
        dst_[tid] = dt[b * Ssz + tid];
    }
    if (wavei == 0) {
        int m = mask[b * Ssz + lane] + mask[b * Ssz + lane + 64];
#pragma unroll
        for (int off = 32; off; off >>= 1) m += __shfl_down(m, off);
        if (lane == 0) len_s = m;
    }
    __syncthreads();                                        // barrier 1

    const int   len = len_s;
    const float bhv = bh_p[0], btv = bt_p[0];
    float* out_impl = out;                                  // [B,4,4]
    float* out_expl = out + Bsz * 16;                       // [B,16,4]
    float* out_hs   = out_expl + Bsz * 64;                  // [B,1024]
    float* out_ts   = out_hs + Bsz * NSPAN;                 // [B,1024]

    // phase 1: thread = (start, grp); grp 0 (waves 0-1) = targets,
    // grp 1 (waves 2-3) = holders. Running sum over widths 1..8; candidates
    // generated in ascending span index (stable: insert_g keeps lower index on tie).
    {
        const int st  = tid & (Ssz - 1);
        const int grp = tid >> 7;
        const float* dar = grp ? dsh : dst_;
        const float  bv  = grp ? bhv : btv;
        float* outp = grp ? (out_hs + b * NSPAN) : (out_ts + b * NSPAN);
        Top4 t4l; t4_init(t4l);
        float run = 0.f;
#pragma unroll
        for (int widx = 0; widx < Msz; ++widx) {
            bool fits = (st < len - widx);
            if (fits) run += dar[st + widx];       // st+widx < len <= Ssz, in-bounds
            bool valid = fits && (grp == 0 || widx < MHs);
            float sc = -1.f;
            if (valid) {
                float x = run * (1.f / (float)(widx + 1)) + bv;
                sc = 1.f / (1.f + __expf(-x));
            }
            int i = (widx << 7) | st;
            outp[i] = sc;
            t4_insert_g(t4l, sc, i);
        }
        t4l = t4_wave_merge(t4l);
        if (lane == 0) {
#pragma unroll
            for (int k = 0; k < 4; ++k) { swv[wavei][k] = t4l.v[k]; swi[wavei][k] = t4l.ix[k]; }
        }
    }
    __syncthreads();                                        // barrier 2

    // cross-wave merge: tid 0 -> targets (waves 0,1 -> slots 0..3),
    //                   tid 1 -> holders (waves 2,3 -> slots 4..7)
    if (tid < 2) {
        Top4 a, c;
#pragma unroll
        for (int k = 0; k < 4; ++k) {
            a.v[k] = swv[2 * tid][k];     a.ix[k] = swi[2 * tid][k];
            c.v[k] = swv[2 * tid + 1][k]; c.ix[k] = swi[2 * tid + 1][k];
        }
        t4_merge_into(a, c);
#pragma unroll
        for (int k = 0; k < 4; ++k) {
            sel[tid * 4 + k] = a.ix[k];
            val[tid * 4 + k] = (a.v[k] > 0.f) ? 1 : 0;
        }
    }
    __syncthreads();                                        // barrier 3

    // phase 2: projections — wave handles slot wavei (target) then wavei+4 (holder).
    // All span-row loads unrolled+clamped -> independent, one latency batch per slot.
    for (int s2 = 0; s2 < 2; ++s2) {
        int slot = wavei + 4 * s2;
        float acc[8] = {0.f, 0.f, 0.f, 0.f, 0.f, 0.f, 0.f, 0.f};
        if (val[slot]) {                                    // wave-uniform branch
            int idx = sel[slot];
            int w = (idx >> 7) + 1, st = idx & (Ssz - 1);
            const float4* base = (const float4*)(emb + ((size_t)b * Ssz + st) * Hsz);
            float inv = 1.f / (float)w;
            float4 s0 = {0,0,0,0}, s1 = {0,0,0,0}, s2v = {0,0,0,0};
#pragma unroll
            for (int r = 0; r < Msz; ++r) {
                int   rr = (r < w) ? r : (w - 1);           // clamped: always a valid row
                float m_ = (r < w) ? inv : 0.f;
                const float4* rp = base + rr * (Hsz / 4);
                float4 e0 = rp[lane];
                float4 e1 = rp[lane + 64];
                float4 e2 = rp[lane + 128];
                s0.x = fmaf(e0.x, m_, s0.x); s0.y = fmaf(e0.y, m_, s0.y);
                s0.z = fmaf(e0.z, m_, s0.z); s0.w = fmaf(e0.w, m_, s0.w);
                s1.x = fmaf(e1.x, m_, s1.x); s1.y = fmaf(e1.y, m_, s1.y);
                s1.z = fmaf(e1.z, m_, s1.z); s1.w = fmaf(e1.w, m_, s1.w);
                s2v.x = fmaf(e2.x, m_, s2v.x); s2v.y = fmaf(e2.y, m_, s2v.y);
                s2v.z = fmaf(e2.z, m_, s2v.z); s2v.w = fmaf(e2.w, m_, s2v.w);
            }
            const float4* wi4 = (const float4*)wi;          // [Hsz][4] -> one float4 per row
            const float4* we4 = (const float4*)we;          // [2*Hsz][4]
#pragma unroll
            for (int ii = 0; ii < 3; ++ii) {
                float4 rep = (ii == 0) ? s0 : ((ii == 1) ? s1 : s2v);
                float reps[4] = {rep.x, rep.y, rep.z, rep.w};
                int j = lane + 64 * ii;                     // float4 index; elements 4j..4j+3
                if (s2 == 0) {                              // target: wi + we bottom half
#pragma unroll
                    for (int t = 0; t < 4; ++t) {
                        float rt = reps[t];
                        float4 a = wi4[4 * j + t];
                        float4 c = we4[Hsz + 4 * j + t];
                        acc[0] = fmaf(rt, a.x, acc[0]); acc[1] = fmaf(rt, a.y, acc[1]);
                        acc[2] = fmaf(rt, a.z, acc[2]); acc[3] = fmaf(rt, a.w, acc[3]);
                        acc[4] = fmaf(rt, c.x, acc[4]); acc[5] = fmaf(rt, c.y, acc[5]);
                        acc[6] = fmaf(rt, c.z, acc[6]); acc[7] = fmaf(rt, c.w, acc[7]);
                    }
                } else {                                    // holder: we top half
#pragma unroll
                    for (int t = 0; t < 4; ++t) {
                        float rt = reps[t];
                        float4 c = we4[4 * j + t];
                        acc[0] = fmaf(rt, c.x, acc[0]); acc[1] = fmaf(rt, c.y, acc[1]);
                        acc[2] = fmaf(rt, c.z, acc[2]); acc[3] = fmaf(rt, c.w, acc[3]);
                    }
                }
            }
        }
#pragma unroll
        for (int off = 32; off; off >>= 1)
#pragma unroll
            for (int c = 0; c < 8; ++c) acc[c] += __shfl_down(acc[c], off);
        if (lane == 0)
#pragma unroll
            for (int c = 0; c < 8; ++c) proj[slot][c] = acc[c];
    }
    __syncthreads();                                        // barrier 4

    // phase 3: final logits
    if (tid < 16) {                 // implicit: [4 targets][4 cols]
        int k = tid >> 2, c = tid & 3;
        out_impl[b * 16 + tid] = bi[c] + (val[k] ? proj[k][c] : 0.f);
    } else if (tid >= 64 && tid < 128) {  // explicit: [4 holders][4 targets][4 cols]
        int u = tid - 64;
        int j = u >> 4, k = (u >> 2) & 3, c = u & 3;
        float v = be[c];
        if (val[4 + j] && val[k]) v += proj[4 + j][c] + proj[k][4 + c];
        out_expl[b * 64 + u] = v;
    }
}

extern "C" void kernel_launch(void* const* d_in, const int* in_sizes, int n_in,
                              void* d_out, int out_size, void* d_ws, size_t ws_size,
                              hipStream_t stream) {
    const float* emb  = (const float*)d_in[0];
    const int*   mask = (const int*)d_in[1];
    const float* wh   = (const float*)d_in[2];
    const float* bh   = (const float*)d_in[3];
    const float* wt   = (const float*)d_in[4];
    const float* bt   = (const float*)d_in[5];
    const float* wi   = (const float*)d_in[6];
    const float* bi   = (const float*)d_in[7];
    const float* we   = (const float*)d_in[8];
    const float* be   = (const float*)d_in[9];
    float* out = (float*)d_out;

    float* dh = (float*)d_ws;           // [B*S]
    float* dt = dh + Bsz * Ssz;         // [B*S]

    // 512 blocks x 4 waves x 2 rows = 4096 rows (B*S)
    row_dots_kernel<<<512, 256, 0, stream>>>(emb, wh, wt, dh, dt);
    per_batch_kernel<<<Bsz, 256, 0, stream>>>(emb, mask, bh, bt, wi, bi, we, be,
                                              dh, dt, out);
}